// Round 1
// baseline (6784.911 us; speedup 1.0000x reference)
//
#include <hip/hip_runtime.h>
#include <math.h>

#define Bdim 32
#define Sdim 128
#define Tdim 50
#define Edim 768
#define Hdim 1024
#define Vdim 32000
#define EH   1792
#define INPD 1536
#define FCB  500    // fc blocks (legacy multi-kernel path)
#define FCB2 250    // fc block-count in persistent path
#define NBLK 256

typedef __bf16 bf16x8 __attribute__((ext_vector_type(8)));
typedef float  f32x4  __attribute__((ext_vector_type(4)));

__device__ __forceinline__ float sigmf(float v){ return 1.0f / (1.0f + expf(-v)); }

__device__ __forceinline__ ushort f2b(float v){
  unsigned int b = __float_as_uint(v);
  unsigned int r = (b + 0x7fffu + ((b >> 16) & 1u)) >> 16;
  return (ushort)r;
}
__device__ __forceinline__ float b2f(ushort u){
  return __uint_as_float(((unsigned int)u) << 16);
}

// ============ f32 -> bf16 convert ============
__global__ __launch_bounds__(256) void cvt_bf16(const float* __restrict__ src,
                                                ushort* __restrict__ dst, int n4){
  int i = blockIdx.x * 256 + threadIdx.x;
  if (i >= n4) return;
  float4 v = *(const float4*)(src + (size_t)i * 4);
  *(ushort4*)(dst + (size_t)i * 4) = make_ushort4(f2b(v.x), f2b(v.y), f2b(v.z), f2b(v.w));
}

__global__ __launch_bounds__(256) void cvt_w1h(const float* __restrict__ aW1,
                                               ushort* __restrict__ dst){
  int i = blockIdx.x * 256 + threadIdx.x;   // 262144 float4 groups
  if (i >= 262144) return;
  int k = (i & 255) * 4;
  int j = i >> 8;
  float4 v = *(const float4*)(aW1 + (size_t)j * EH + Edim + k);
  *(ushort4*)(dst + (size_t)j * 1024 + k) = make_ushort4(f2b(v.x), f2b(v.y), f2b(v.z), f2b(v.w));
}

__global__ __launch_bounds__(256) void zero_kernel(float* __restrict__ p, int n){
  int i = blockIdx.x * 256 + threadIdx.x;
  if (i < n) p[i] = 0.0f;
}

// ============ gather embeddings -> packed bf16 [k/8][b][8] (k<768) ============
__global__ __launch_bounds__(256) void gather_emb_p(const int* __restrict__ tseq,
                                                    const float* __restrict__ emb,
                                                    ushort* __restrict__ inpP){
  int g = blockIdx.x * 256 + threadIdx.x;   // T*B*96 groups of 8
  if (g >= Tdim * Bdim * 96) return;
  int kb = g % 96;
  int r = g / 96;
  int b = r % Bdim;
  int t = r / Bdim;
  int tok = tseq[b * Tdim + t];
  const float* src = emb + (size_t)tok * Edim + kb * 8;
  float4 a = *(const float4*)src;
  float4 c = *(const float4*)(src + 4);
  ushort* dst = inpP + (size_t)t * 49152 + kb * 256 + b * 8;
  *(ushort4*)(dst)     = make_ushort4(f2b(a.x), f2b(a.y), f2b(a.z), f2b(a.w));
  *(ushort4*)(dst + 4) = make_ushort4(f2b(c.x), f2b(c.y), f2b(c.z), f2b(c.w));
}

// ============ xW = x @ W1x^T -> bf16 (setup) ============
__global__ __launch_bounds__(256) void xw_gemm(const float* __restrict__ x,
                                               const float* __restrict__ w1,
                                               ushort* __restrict__ xWb){
  __shared__ float As[16][68];
  __shared__ float Ws[16][68];
  int tid = threadIdx.x;
  int m0 = blockIdx.x * 64;
  int n0 = blockIdx.y * 64;
  int lm = tid >> 2;
  int lk = (tid & 3) << 2;
  int tm = (tid >> 4) << 2;
  int tn = (tid & 15) << 2;
  float acc[4][4] = {};
  for (int k0 = 0; k0 < Edim; k0 += 16){
    float4 av = *(const float4*)&x [(size_t)(m0 + lm) * Edim + k0 + lk];
    float4 wv = *(const float4*)&w1[(size_t)(n0 + lm) * EH   + k0 + lk];
    As[lk+0][lm] = av.x; As[lk+1][lm] = av.y; As[lk+2][lm] = av.z; As[lk+3][lm] = av.w;
    Ws[lk+0][lm] = wv.x; Ws[lk+1][lm] = wv.y; Ws[lk+2][lm] = wv.z; Ws[lk+3][lm] = wv.w;
    __syncthreads();
#pragma unroll
    for (int k = 0; k < 16; k++){
      float a0 = As[k][tm+0], a1 = As[k][tm+1], a2 = As[k][tm+2], a3 = As[k][tm+3];
      float b0 = Ws[k][tn+0], b1 = Ws[k][tn+1], b2 = Ws[k][tn+2], b3 = Ws[k][tn+3];
      acc[0][0] += a0*b0; acc[0][1] += a0*b1; acc[0][2] += a0*b2; acc[0][3] += a0*b3;
      acc[1][0] += a1*b0; acc[1][1] += a1*b1; acc[1][2] += a1*b2; acc[1][3] += a1*b3;
      acc[2][0] += a2*b0; acc[2][1] += a2*b1; acc[2][2] += a2*b2; acc[2][3] += a2*b3;
      acc[3][0] += a3*b0; acc[3][1] += a3*b1; acc[3][2] += a3*b2; acc[3][3] += a3*b3;
    }
    __syncthreads();
  }
#pragma unroll
  for (int i = 0; i < 4; i++)
#pragma unroll
    for (int j = 0; j < 4; j++)
      xWb[(size_t)(m0 + tm + i) * Hdim + n0 + tn + j] = f2b(acc[i][j]);
}

// ============ one-time transpose x_bf [b][s][e] -> xT [b][e][s] ============
__global__ __launch_bounds__(256) void xpose_x(const ushort* __restrict__ xbf,
                                               ushort* __restrict__ xT){
  __shared__ ushort tl[64][132];
  int b  = blockIdx.x / 12;
  int et = blockIdx.x % 12;
  int e0 = et * 64;
  int el = threadIdx.x & 63;
  int s4 = threadIdx.x >> 6;
#pragma unroll
  for (int s0 = 0; s0 < Sdim; s0 += 4){
    int s = s0 + s4;
    tl[el][s] = xbf[((size_t)(b * Sdim + s)) * Edim + e0 + el];
  }
  __syncthreads();
  int e  = threadIdx.x >> 2;
  int sc = (threadIdx.x & 3) * 32;
  ushort* dst = xT + ((size_t)b * Edim + e0 + e) * Sdim + sc;
#pragma unroll
  for (int i = 0; i < 4; i++)
    *(ushort4*)(dst + i * 8) = *(ushort4*)&tl[e][sc + i * 8];
}

// ============ MFMA tile: per-lane A-row r, 32 b cols, K-range ============
// A row-major (lda elems). B packed [k/8][32][8]. D: tile-row=(lane>>4)*4+reg, col=lane&15.
template<bool ABF16>
__device__ __forceinline__ void mfma_tile(const void* A, int lda, int r,
                                          const ushort* __restrict__ Bp,
                                          int kbeg, int klen, int lane,
                                          f32x4& acc0, f32x4& acc1){
  int q = lane >> 4;
  const ushort* Ab = (const ushort*)A;
  const float*  Af = (const float*)A;
#pragma unroll 4
  for (int kk = kbeg; kk < kbeg + klen; kk += 32){
    bf16x8 a;
    if (ABF16){
      a = *reinterpret_cast<const bf16x8*>(Ab + (size_t)r * lda + kk + q * 8);
    } else {
      const float* p = Af + (size_t)r * lda + kk + q * 8;
      float4 u = *(const float4*)p;
      float4 w = *(const float4*)(p + 4);
      union { ushort s[8]; bf16x8 v; } t;
      t.s[0]=f2b(u.x); t.s[1]=f2b(u.y); t.s[2]=f2b(u.z); t.s[3]=f2b(u.w);
      t.s[4]=f2b(w.x); t.s[5]=f2b(w.y); t.s[6]=f2b(w.z); t.s[7]=f2b(w.w);
      a = t.v;
    }
    const ushort* bbase = Bp + ((kk >> 3) + q) * 256 + (lane & 15) * 8;
    bf16x8 b0 = *reinterpret_cast<const bf16x8*>(bbase);
    bf16x8 b1 = *reinterpret_cast<const bf16x8*>(bbase + 128);
    acc0 = __builtin_amdgcn_mfma_f32_16x16x32_bf16(a, b0, acc0, 0, 0, 0);
    acc1 = __builtin_amdgcn_mfma_f32_16x16x32_bf16(a, b1, acc1, 0, 0, 0);
  }
}

// =============== legacy multi-kernel path (used when workspace too small) ===============
template<bool ABF16>
__global__ __launch_bounds__(256) void lstm_layer(const void* __restrict__ Wih, int Kin,
                                                  const void* __restrict__ Whh,
                                                  const ushort* __restrict__ inpP,
                                                  const ushort* __restrict__ hP,
                                                  const float* __restrict__ bih,
                                                  const float* __restrict__ bhh,
                                                  const float* __restrict__ cold,
                                                  float* __restrict__ cnew,
                                                  ushort* __restrict__ hPack){
  __shared__ float ld[4][4][4][32];   // [kq][gate][unit][b]
  int tid = threadIdx.x;
  int lane = tid & 63, kq = tid >> 6;
  int j0 = blockIdx.x * 4;
  int r = ((lane & 15) >> 2) * 1024 + j0 + (lane & 3);
  f32x4 acc0 = {0,0,0,0}, acc1 = {0,0,0,0};
  int kin_q = Kin >> 2;
  mfma_tile<ABF16>(Wih, Kin, r, inpP, kq * kin_q, kin_q, lane, acc0, acc1);
  mfma_tile<ABF16>(Whh, Hdim, r, hP, kq * 256, 256, lane, acc0, acc1);
  int g = lane >> 4, c = lane & 15;
#pragma unroll
  for (int rr = 0; rr < 4; rr++){
    ld[kq][g][rr][c]      = acc0[rr];
    ld[kq][g][rr][c + 16] = acc1[rr];
  }
  __syncthreads();
  if (tid < 128){
    int b = tid & 31, ul = tid >> 5;
    int j = j0 + ul;
    float gi = 0, gf = 0, gg = 0, go = 0;
#pragma unroll
    for (int k = 0; k < 4; k++){
      gi += ld[k][0][ul][b];
      gf += ld[k][1][ul][b];
      gg += ld[k][2][ul][b];
      go += ld[k][3][ul][b];
    }
    gi += bih[j]        + bhh[j];
    gf += bih[j + 1024] + bhh[j + 1024];
    gg += bih[j + 2048] + bhh[j + 2048];
    go += bih[j + 3072] + bhh[j + 3072];
    float cv = sigmf(gf) * cold[j * 32 + b] + sigmf(gi) * tanhf(gg);
    float hv = sigmf(go) * tanhf(cv);
    cnew[j * 32 + b] = cv;
    hPack[(j >> 3) * 256 + b * 8 + (j & 7)] = f2b(hv);
  }
}

__global__ __launch_bounds__(256) void attn_a_gemm(const ushort* __restrict__ W1h,
                                                   const ushort* __restrict__ h2P,
                                                   const float* __restrict__ b1,
                                                   float* __restrict__ aBuf){
  __shared__ float ld[4][32][17];
  int tid = threadIdx.x;
  int lane = tid & 63, kq = tid >> 6;
  int rowBase = blockIdx.x * 16;
  int r = rowBase + (lane & 15);
  f32x4 acc0 = {0,0,0,0}, acc1 = {0,0,0,0};
  mfma_tile<true>(W1h, Hdim, r, h2P, kq * 256, 256, lane, acc0, acc1);
  int q = lane >> 4, c = lane & 15;
#pragma unroll
  for (int rr = 0; rr < 4; rr++){
    ld[kq][c][q * 4 + rr]      = acc0[rr];
    ld[kq][c + 16][q * 4 + rr] = acc1[rr];
  }
  __syncthreads();
  int b = tid & 31, jl = tid >> 5;
#pragma unroll
  for (int h = 0; h < 2; h++){
    int j2 = jl + h * 8;
    float v = ld[0][b][j2] + ld[1][b][j2] + ld[2][b][j2] + ld[3][b][j2];
    int j = rowBase + j2;
    aBuf[b * 1024 + j] = v + b1[j];
  }
}

__global__ __launch_bounds__(256) void attn_score(const float* __restrict__ aBuf,
                                                  const float* __restrict__ w2,
                                                  const float* __restrict__ b2p,
                                                  const ushort* __restrict__ xWb,
                                                  float* __restrict__ scBuf){
  int b = blockIdx.x >> 2, sg = blockIdx.x & 3;
  int w = threadIdx.x >> 6, lane = threadIdx.x & 63;
  int jb = lane * 16;
  float ab[16], wv[16];
#pragma unroll
  for (int i = 0; i < 4; i++){
    *(float4*)&ab[i * 4] = *(const float4*)&aBuf[b * 1024 + jb + i * 4];
    *(float4*)&wv[i * 4] = *(const float4*)&w2[jb + i * 4];
  }
  float b2v = b2p[0];
#pragma unroll
  for (int si = 0; si < 8; si++){
    int s = sg * 32 + w * 8 + si;
    const ushort* xrow = xWb + (size_t)(b * Sdim + s) * Hdim + jb;
    bf16x8 x0 = *reinterpret_cast<const bf16x8*>(xrow);
    bf16x8 x1 = *reinterpret_cast<const bf16x8*>(xrow + 8);
    float acc = 0.0f;
#pragma unroll
    for (int i = 0; i < 8; i++){
      float h0 = fmaxf((float)x0[i] + ab[i], 0.0f);
      float h1 = fmaxf((float)x1[i] + ab[i + 8], 0.0f);
      acc += h0 * wv[i] + h1 * wv[i + 8];
    }
    for (int off = 32; off; off >>= 1) acc += __shfl_xor(acc, off);
    if (lane == 0) scBuf[b * Sdim + s] = acc + b2v;
  }
}

__global__ __launch_bounds__(256) void attn_ctx2(const float* __restrict__ scBuf,
                                                 const ushort* __restrict__ xbf,
                                                 ushort* __restrict__ inpPt){
  __shared__ float sb[Sdim];
  int b = blockIdx.x / 3, ec = blockIdx.x % 3;
  int tid = threadIdx.x;
  if (tid < Sdim) sb[tid] = scBuf[b * Sdim + tid];
  __syncthreads();
  if (tid < 64){
    float v0 = sb[tid], v1 = sb[tid + 64];
    float m = fmaxf(v0, v1);
    for (int off = 32; off; off >>= 1) m = fmaxf(m, __shfl_xor(m, off));
    float e = expf(v0 - m) + expf(v1 - m);
    for (int off = 32; off; off >>= 1) e += __shfl_xor(e, off);
    float lse = m + logf(e);
    sb[tid]      = v0 - lse;
    sb[tid + 64] = v1 - lse;
  }
  __syncthreads();
  int e = ec * 256 + tid;
  const ushort* xb = xbf + (size_t)b * Sdim * Edim + e;
  float acc = 0.0f;
#pragma unroll 8
  for (int s = 0; s < Sdim; s++) acc += sb[s] * b2f(xb[(size_t)s * Edim]);
  int k = Edim + e;
  inpPt[(k >> 3) * 256 + b * 8 + (k & 7)] = f2b(acc);
}

template<bool ABF16>
__global__ __launch_bounds__(512) void fc_gemm(const void* __restrict__ fcW,
                                               const ushort* __restrict__ hP,
                                               const float* __restrict__ fcb,
                                               float* __restrict__ logits,
                                               float* __restrict__ partM,
                                               float* __restrict__ partS){
  __shared__ float ld[2][32][73];
  int tid = threadIdx.x;
  int lane = tid & 63, w = tid >> 6;
  int khalf = w >> 2;
  int v0 = blockIdx.x * 64 + (w & 3) * 16;
  int r = v0 + (lane & 15);
  f32x4 acc0 = {0,0,0,0}, acc1 = {0,0,0,0};
  mfma_tile<ABF16>(fcW, Hdim, r, hP, khalf * 512, 512, lane, acc0, acc1);
  int q = lane >> 4, c = lane & 15;
#pragma unroll
  for (int rr = 0; rr < 4; rr++){
    int vloc = (w & 3) * 16 + q * 4 + rr;
    ld[khalf][c][vloc]      = acc0[rr];
    ld[khalf][c + 16][vloc] = acc1[rr];
  }
  __syncthreads();
  int b = tid >> 4, i0 = (tid & 15) * 4;
  int vg = blockIdx.x * 64 + i0;
  float o0 = ld[0][b][i0+0] + ld[1][b][i0+0] + fcb[vg+0];
  float o1 = ld[0][b][i0+1] + ld[1][b][i0+1] + fcb[vg+1];
  float o2 = ld[0][b][i0+2] + ld[1][b][i0+2] + fcb[vg+2];
  float o3 = ld[0][b][i0+3] + ld[1][b][i0+3] + fcb[vg+3];
  *(float4*)&logits[(size_t)b * Vdim + vg] = make_float4(o0, o1, o2, o3);
  float m = fmaxf(fmaxf(o0, o1), fmaxf(o2, o3));
  float s = expf(o0 - m) + expf(o1 - m) + expf(o2 - m) + expf(o3 - m);
#pragma unroll
  for (int off = 1; off < 16; off <<= 1){
    float m2 = __shfl_xor(m, off);
    float s2 = __shfl_xor(s, off);
    float nm = fmaxf(m, m2);
    s = s * expf(m - nm) + s2 * expf(m2 - nm);
    m = nm;
  }
  if ((tid & 15) == 0){
    partM[b * FCB + blockIdx.x] = m;
    partS[b * FCB + blockIdx.x] = s;
  }
}

__global__ __launch_bounds__(256) void lsm_write(const float* __restrict__ logits,
                                                 const float* __restrict__ partM,
                                                 const float* __restrict__ partS,
                                                 float* __restrict__ out, int t){
  __shared__ float sm[256], ss[256];
  int b = blockIdx.x, chunk = blockIdx.y;
  int tid = threadIdx.x;
  float m = -1e30f, s = 0.0f;
  for (int i = tid; i < FCB; i += 256){
    float m2 = partM[b * FCB + i];
    float s2 = partS[b * FCB + i];
    float nm = fmaxf(m, m2);
    s = s * expf(m - nm) + s2 * expf(m2 - nm);
    m = nm;
  }
  sm[tid] = m; ss[tid] = s;
  __syncthreads();
  for (int r = 128; r; r >>= 1){
    if (tid < r){
      float m2 = sm[tid + r], s2 = ss[tid + r];
      float nm = fmaxf(sm[tid], m2);
      ss[tid] = ss[tid] * expf(sm[tid] - nm) + s2 * expf(m2 - nm);
      sm[tid] = nm;
    }
    __syncthreads();
  }
  float lse = sm[0] + logf(ss[0]);
  if (tid < 250){
    int i4 = chunk * 250 + tid;
    float4 v = ((const float4*)logits)[(size_t)b * 8000 + i4];
    float4* dst = (float4*)(out + ((size_t)b * Tdim + t) * Vdim);
    dst[i4] = make_float4(v.x - lse, v.y - lse, v.z - lse, v.w - lse);
  }
}

// ====================== persistent whole-decode kernel ======================
struct PArgs {
  const ushort *W1h, *xW, *xT, *fcWb;
  const ushort *Wih0, *Whh0, *Wih1, *Whh1, *Wih2, *Whh2;
  ushort *inpP, *hPackB;
  const float *ab1, *aW2, *ab2, *fcb;
  const float *bih0, *bhh0, *bih1, *bhh1, *bih2, *bhh2;
  float *aBuf, *partM, *partS, *logits, *cBuf, *out;
  unsigned *bar;
};

union ShU {
  float a8[8][32][17];          // stage A combine   (17408 B -> union size)
  float sb[Sdim];               // stage B scores
  float ll[8][4][4][32];        // lstm combine      (16384 B)
  float fc[32][132];            // fc combine        (16896 B)
  struct { float sm[512]; float ss[512]; } g;  // stage G
};

// Grid barrier: 8 bucket counters (256B apart) -> root -> generation flag.
// Relaxed atomics + explicit __threadfence() release/acquire. Bounded spin:
// a co-residency failure degrades to a wrong answer, never a hang.
__device__ __forceinline__ void gridbar(unsigned* bar){
  __syncthreads();
  if (threadIdx.x == 0){
    __threadfence();                               // release my block's stores
    unsigned* gp = bar + 576;
    unsigned g = __hip_atomic_load(gp, __ATOMIC_RELAXED, __HIP_MEMORY_SCOPE_AGENT);
    unsigned* cnt = bar + (blockIdx.x & 7) * 64;
    unsigned a = __hip_atomic_fetch_add(cnt, 1u, __ATOMIC_RELAXED, __HIP_MEMORY_SCOPE_AGENT);
    if (a == 31u){                                 // last of my 32-block bucket
      __hip_atomic_store(cnt, 0u, __ATOMIC_RELAXED, __HIP_MEMORY_SCOPE_AGENT);
      __threadfence();                             // order reset before root add
      unsigned r = __hip_atomic_fetch_add(bar + 512, 1u, __ATOMIC_RELAXED, __HIP_MEMORY_SCOPE_AGENT);
      if (r == 7u){
        __hip_atomic_store(bar + 512, 0u, __ATOMIC_RELAXED, __HIP_MEMORY_SCOPE_AGENT);
        __threadfence();
        __hip_atomic_store(gp, g + 1u, __ATOMIC_RELAXED, __HIP_MEMORY_SCOPE_AGENT);
      }
    }
    int guard = 0;
    while (__hip_atomic_load(gp, __ATOMIC_RELAXED, __HIP_MEMORY_SCOPE_AGENT) == g){
      __builtin_amdgcn_s_sleep(2);
      if (++guard > 300000) break;                 // ~30ms escape hatch
    }
    __threadfence();                               // acquire others' stores
  }
  __syncthreads();
}

__device__ __forceinline__ void lstm_stage(ShU& sh, const ushort* Wih, int Kin,
                                           const ushort* Whh, const ushort* bin,
                                           const ushort* hOld,
                                           const float* bihL, const float* bhhL,
                                           const float* cOld, float* cNew,
                                           ushort* hNew, int tid, int lane, int wid,
                                           int blk){
  int j0 = blk * 4;
  int r = ((lane & 15) >> 2) * 1024 + j0 + (lane & 3);
  f32x4 acc0 = {0,0,0,0}, acc1 = {0,0,0,0};
  int ke = Kin >> 3;                                 // K split across 8 waves
  mfma_tile<true>(Wih, Kin, r, bin, wid * ke, ke, lane, acc0, acc1);
  mfma_tile<true>(Whh, Hdim, r, hOld, wid * 128, 128, lane, acc0, acc1);
  int g = lane >> 4, c = lane & 15;
#pragma unroll
  for (int rr = 0; rr < 4; rr++){
    sh.ll[wid][g][rr][c]      = acc0[rr];
    sh.ll[wid][g][rr][c + 16] = acc1[rr];
  }
  __syncthreads();
  if (tid < 128){
    int b = tid & 31, ul = tid >> 5;
    int j = j0 + ul;
    float gi = 0, gf = 0, gg = 0, go = 0;
#pragma unroll
    for (int k = 0; k < 8; k++){
      gi += sh.ll[k][0][ul][b];
      gf += sh.ll[k][1][ul][b];
      gg += sh.ll[k][2][ul][b];
      go += sh.ll[k][3][ul][b];
    }
    gi += bihL[j]        + bhhL[j];
    gf += bihL[j + 1024] + bhhL[j + 1024];
    gg += bihL[j + 2048] + bhhL[j + 2048];
    go += bihL[j + 3072] + bhhL[j + 3072];
    float cv = sigmf(gf) * cOld[j * 32 + b] + sigmf(gi) * tanhf(gg);
    float hv = sigmf(go) * tanhf(cv);
    cNew[j * 32 + b] = cv;
    hNew[(j >> 3) * 256 + b * 8 + (j & 7)] = f2b(hv);
  }
}

__global__ __launch_bounds__(512, 2) void persistent_all(PArgs p){
  extern __shared__ char smem[];                 // 84KB requested -> forces 1 block/CU
  ShU& sh = *reinterpret_cast<ShU*>(smem);
  int tid  = threadIdx.x;
  int blk  = blockIdx.x;
  int lane = tid & 63;
  int wid  = tid >> 6;

  for (int t = 0; t < Tdim; t++){
    int pn = t & 1, po = 1 - pn;
    ushort* inpPt = p.inpP + (size_t)t * 49152;
    const ushort* h2old = p.hPackB + (size_t)(2 * 2 + po) * 32768;

    // ---------- stage A: aBuf = h2_old @ W1h^T + b1  (blocks 0..63) ----------
    if (blk < 64){
      int rowBase = blk * 16;
      int r = rowBase + (lane & 15);
      f32x4 acc0 = {0,0,0,0}, acc1 = {0,0,0,0};
      mfma_tile<true>(p.W1h, Hdim, r, h2old, wid * 128, 128, lane, acc0, acc1);
      int q = lane >> 4, c = lane & 15;
#pragma unroll
      for (int rr = 0; rr < 4; rr++){
        sh.a8[wid][c][q * 4 + rr]      = acc0[rr];
        sh.a8[wid][c + 16][q * 4 + rr] = acc1[rr];
      }
      __syncthreads();
      int b = tid & 31, jl = tid >> 5;                 // 512 thr = 32 b x 16 j
      float v = 0;
#pragma unroll
      for (int k = 0; k < 8; k++) v += sh.a8[k][b][jl];
      int j = rowBase + jl;
      p.aBuf[b * 1024 + j] = v + p.ab1[j];
    }
    gridbar(p.bar);

    // ---------- stage B: scores + log-softmax + context (blocks 0..31, one per b) ----------
    if (blk < 32){
      int b = blk;
      int jb = lane * 16;
      float ab[16], w2r[16];
#pragma unroll
      for (int i = 0; i < 4; i++){
        *(float4*)&ab[i * 4]  = *(const float4*)&p.aBuf[b * 1024 + jb + i * 4];
        *(float4*)&w2r[i * 4] = *(const float4*)&p.aW2[jb + i * 4];
      }
      float b2v = p.ab2[0];
#pragma unroll 2
      for (int si = 0; si < 16; si++){
        int s = wid * 16 + si;
        const ushort* xrow = p.xW + (size_t)(b * Sdim + s) * Hdim + jb;
        bf16x8 x0 = *reinterpret_cast<const bf16x8*>(xrow);
        bf16x8 x1 = *reinterpret_cast<const bf16x8*>(xrow + 8);
        float acc = 0.0f;
#pragma unroll
        for (int i = 0; i < 8; i++){
          float h0 = fmaxf((float)x0[i] + ab[i], 0.0f);
          float h1 = fmaxf((float)x1[i] + ab[i + 8], 0.0f);
          acc += h0 * w2r[i] + h1 * w2r[i + 8];
        }
        for (int off = 32; off; off >>= 1) acc += __shfl_xor(acc, off);
        if (lane == 0) sh.sb[s] = acc + b2v;
      }
      __syncthreads();
      if (tid < 64){
        float v0 = sh.sb[tid], v1 = sh.sb[tid + 64];
        float m = fmaxf(v0, v1);
        for (int off = 32; off; off >>= 1) m = fmaxf(m, __shfl_xor(m, off));
        float e = expf(v0 - m) + expf(v1 - m);
        for (int off = 32; off; off >>= 1) e += __shfl_xor(e, off);
        float lse = m + logf(e);
        sh.sb[tid]      = v0 - lse;
        sh.sb[tid + 64] = v1 - lse;
      }
      __syncthreads();
#pragma unroll
      for (int half = 0; half < 2; half++){
        int e = half * 512 + tid;
        if (e < Edim){
          const ushort* xr = p.xT + ((size_t)b * Edim + e) * Sdim;
          float acc = 0.0f;
#pragma unroll
          for (int s8 = 0; s8 < 16; s8++){
            bf16x8 xv = *reinterpret_cast<const bf16x8*>(xr + s8 * 8);
#pragma unroll
            for (int k = 0; k < 8; k++) acc += sh.sb[s8 * 8 + k] * (float)xv[k];
          }
          int kk = Edim + e;
          inpPt[(kk >> 3) * 256 + b * 8 + (kk & 7)] = f2b(acc);
        }
      }
    }
    gridbar(p.bar);

    // ---------- stages C/D/E: 3 LSTM layers (all 256 blocks) ----------
    {
      ushort* hb = p.hPackB;  float* cb = p.cBuf;
      lstm_stage(sh, p.Wih0, INPD, p.Whh0, inpPt,
                 hb + (0 * 2 + po) * 32768, p.bih0, p.bhh0,
                 cb + (0 * 2 + po) * 32768, cb + (0 * 2 + pn) * 32768,
                 hb + (0 * 2 + pn) * 32768, tid, lane, wid, blk);
      gridbar(p.bar);
      lstm_stage(sh, p.Wih1, Hdim, p.Whh1, hb + (0 * 2 + pn) * 32768,
                 hb + (1 * 2 + po) * 32768, p.bih1, p.bhh1,
                 cb + (1 * 2 + po) * 32768, cb + (1 * 2 + pn) * 32768,
                 hb + (1 * 2 + pn) * 32768, tid, lane, wid, blk);
      gridbar(p.bar);
      lstm_stage(sh, p.Wih2, Hdim, p.Whh2, hb + (1 * 2 + pn) * 32768,
                 hb + (2 * 2 + po) * 32768, p.bih2, p.bhh2,
                 cb + (2 * 2 + po) * 32768, cb + (2 * 2 + pn) * 32768,
                 hb + (2 * 2 + pn) * 32768, tid, lane, wid, blk);
      gridbar(p.bar);
    }

    // ---------- stage F: fc logits + softmax partials (blocks 0..249, 128 rows each) ----------
    if (blk < FCB2){
      const ushort* h2new = p.hPackB + (size_t)(2 * 2 + pn) * 32768;
      int v0 = blk * 128 + wid * 16;
      int r = v0 + (lane & 15);
      f32x4 acc0 = {0,0,0,0}, acc1 = {0,0,0,0};
      mfma_tile<true>(p.fcWb, Hdim, r, h2new, 0, Hdim, lane, acc0, acc1);
      int q = lane >> 4, c = lane & 15;
#pragma unroll
      for (int rr = 0; rr < 4; rr++){
        sh.fc[c][wid * 16 + q * 4 + rr]      = acc0[rr];
        sh.fc[c + 16][wid * 16 + q * 4 + rr] = acc1[rr];
      }
      __syncthreads();
      int b = tid >> 4, i0 = (tid & 15) * 8;           // 32 b x 16 thr x 8 v
      int vg = blk * 128 + i0;
      float o[8];
#pragma unroll
      for (int j = 0; j < 8; j++) o[j] = sh.fc[b][i0 + j] + p.fcb[vg + j];
      *(float4*)&p.logits[(size_t)b * Vdim + vg]     = make_float4(o[0], o[1], o[2], o[3]);
      *(float4*)&p.logits[(size_t)b * Vdim + vg + 4] = make_float4(o[4], o[5], o[6], o[7]);
      float m = o[0];
#pragma unroll
      for (int j = 1; j < 8; j++) m = fmaxf(m, o[j]);
      float s = 0.0f;
#pragma unroll
      for (int j = 0; j < 8; j++) s += expf(o[j] - m);
#pragma unroll
      for (int off = 1; off < 16; off <<= 1){
        float m2 = __shfl_xor(m, off);
        float s2 = __shfl_xor(s, off);
        float nm = fmaxf(m, m2);
        s = s * expf(m - nm) + s2 * expf(m2 - nm);
        m = nm;
      }
      if ((tid & 15) == 0){
        p.partM[b * FCB2 + blk] = m;
        p.partS[b * FCB2 + blk] = s;
      }
    }
    gridbar(p.bar);

    // ---------- stage G: lse finalize + out write (all blocks; 8 per b) ----------
    {
      int b = blk >> 3, chunk = blk & 7;
      float m = -1e30f, s = 0.0f;
      if (tid < FCB2){ m = p.partM[b * FCB2 + tid]; s = p.partS[b * FCB2 + tid]; }
      sh.g.sm[tid] = m; sh.g.ss[tid] = s;
      __syncthreads();
      for (int rr = 256; rr > 0; rr >>= 1){
        if (tid < rr){
          float m2 = sh.g.sm[tid + rr], s2 = sh.g.ss[tid + rr];
          float nm = fmaxf(sh.g.sm[tid], m2);
          sh.g.ss[tid] = sh.g.ss[tid] * expf(sh.g.sm[tid] - nm) + s2 * expf(m2 - nm);
          sh.g.sm[tid] = nm;
        }
        __syncthreads();
      }
      float lse = sh.g.sm[0] + logf(sh.g.ss[0]);
      const float4* lg = (const float4*)(p.logits + (size_t)b * Vdim);
      float4* dst = (float4*)(p.out + ((size_t)b * Tdim + t) * Vdim);
#pragma unroll
      for (int it = 0; it < 2; it++){
        int i4 = chunk * 1000 + it * 512 + tid;
        if (i4 < chunk * 1000 + 1000){
          float4 v = lg[i4];
          dst[i4] = make_float4(v.x - lse, v.y - lse, v.z - lse, v.w - lse);
        }
      }
    }
    // no barrier here: stage G's reads (logits/partM) are not rewritten until
    // next step's stage F, which is 5 barriers away; its write (out[t]) is
    // read by nobody. Next stage A's writes (aBuf) were last read in B(t).
  }
}

// =====================================================================
extern "C" void kernel_launch(void* const* d_in, const int* in_sizes, int n_in,
                              void* d_out, int out_size, void* d_ws, size_t ws_size,
                              hipStream_t stream){
  const float* x    = (const float*)d_in[0];
  const int*   tseq = (const int*)  d_in[1];
  const float* emb  = (const float*)d_in[2];
  const float* aW1  = (const float*)d_in[3];
  const float* ab1  = (const float*)d_in[4];
  const float* aW2  = (const float*)d_in[5];
  const float* ab2  = (const float*)d_in[6];
  const float* fcW  = (const float*)d_in[7];
  const float* fcb  = (const float*)d_in[8];
  const float* Wih[3] = {(const float*)d_in[9],  (const float*)d_in[13], (const float*)d_in[17]};
  const float* Whh[3] = {(const float*)d_in[10], (const float*)d_in[14], (const float*)d_in[18]};
  const float* bih[3] = {(const float*)d_in[11], (const float*)d_in[15], (const float*)d_in[19]};
  const float* bhh[3] = {(const float*)d_in[12], (const float*)d_in[16], (const float*)d_in[20]};
  float* out = (float*)d_out;

  // ---- workspace carve-up ----
  char* p = (char*)d_ws;
  ushort* xW_bf  = (ushort*)p;            p += (size_t)4096 * 1024 * 2;       // 8.39 MB
  ushort* W1h_bf = (ushort*)p;            p += (size_t)1024 * 1024 * 2;       // 2.10 MB
  ushort* inpP   = (ushort*)p;            p += (size_t)Tdim * 49152 * 2;      // 4.92 MB
  ushort* x_bf   = (ushort*)p;            p += (size_t)Bdim * Sdim * Edim * 2;// 6.29 MB
  float*  aBuf   = (float*)p;             p += (size_t)Bdim * Hdim * 4;       // 128 KB
  float*  scBuf  = (float*)p;             p += (size_t)Bdim * Sdim * 4;
  float*  partM  = (float*)p;             p += (size_t)Bdim * FCB * 4;
  float*  partS  = (float*)p;             p += (size_t)Bdim * FCB * 4;
  float*  logits = (float*)p;             p += (size_t)Bdim * Vdim * 4;       // 4.10 MB
  float*  cBuf   = (float*)p;             p += (size_t)6 * 32768 * 4;
  ushort* hPackB = (ushort*)p;            p += (size_t)6 * 32768 * 2;         // contiguous after cBuf
  unsigned* barBuf = (unsigned*)p;        p += (size_t)1024 * 4;              // contiguous after hPackB
  ushort* fcW_bf  = (ushort*)p;           p += (size_t)Vdim * Hdim * 2;       // 65.5 MB
  ushort* Wih_bf[3]; ushort* Whh_bf[3];
  Wih_bf[0] = (ushort*)p;                 p += (size_t)4096 * 1536 * 2;
  Whh_bf[0] = (ushort*)p;                 p += (size_t)4096 * 1024 * 2;
  Wih_bf[1] = (ushort*)p;                 p += (size_t)4096 * 1024 * 2;
  Whh_bf[1] = (ushort*)p;                 p += (size_t)4096 * 1024 * 2;
  Wih_bf[2] = (ushort*)p;                 p += (size_t)4096 * 1024 * 2;
  Whh_bf[2] = (ushort*)p;                 p += (size_t)4096 * 1024 * 2;
  ushort* xT_bf = (ushort*)p;             p += (size_t)Bdim * Edim * Sdim * 2;// 6.29 MB
  size_t need_full = (size_t)(p - (char*)d_ws);
  bool full = ws_size >= need_full;

  // ---- setup ----
  zero_kernel<<<(295936 + 255) / 256, 256, 0, stream>>>(cBuf, 295936);  // cBuf + hPackB + barBuf
  gather_emb_p<<<(Tdim * Bdim * 96 + 255) / 256, 256, 0, stream>>>(tseq, emb, inpP);
  cvt_w1h<<<262144 / 256, 256, 0, stream>>>(aW1, W1h_bf);
  cvt_bf16<<<(Bdim * Sdim * Edim / 4 + 255) / 256, 256, 0, stream>>>(x, x_bf, Bdim * Sdim * Edim / 4);
  xw_gemm<<<dim3(64, 16), 256, 0, stream>>>(x, aW1, xW_bf);
  if (full){
    xpose_x<<<Bdim * 12, 256, 0, stream>>>(x_bf, xT_bf);
    cvt_bf16<<<(Vdim * Hdim / 4 + 255) / 256, 256, 0, stream>>>(fcW, fcW_bf, Vdim * Hdim / 4);
    cvt_bf16<<<(4096 * 1536 / 4 + 255) / 256, 256, 0, stream>>>(Wih[0], Wih_bf[0], 4096 * 1536 / 4);
    cvt_bf16<<<(4096 * 1024 / 4 + 255) / 256, 256, 0, stream>>>(Whh[0], Whh_bf[0], 4096 * 1024 / 4);
    cvt_bf16<<<(4096 * 1024 / 4 + 255) / 256, 256, 0, stream>>>(Wih[1], Wih_bf[1], 4096 * 1024 / 4);
    cvt_bf16<<<(4096 * 1024 / 4 + 255) / 256, 256, 0, stream>>>(Whh[1], Whh_bf[1], 4096 * 1024 / 4);
    cvt_bf16<<<(4096 * 1024 / 4 + 255) / 256, 256, 0, stream>>>(Wih[2], Wih_bf[2], 4096 * 1024 / 4);
    cvt_bf16<<<(4096 * 1024 / 4 + 255) / 256, 256, 0, stream>>>(Whh[2], Whh_bf[2], 4096 * 1024 / 4);

    hipFuncSetAttribute(reinterpret_cast<const void*>(persistent_all),
                        hipFuncAttributeMaxDynamicSharedMemorySize, 86016);
    PArgs pa;
    pa.W1h = W1h_bf; pa.xW = xW_bf; pa.xT = xT_bf; pa.fcWb = fcW_bf;
    pa.Wih0 = Wih_bf[0]; pa.Whh0 = Whh_bf[0];
    pa.Wih1 = Wih_bf[1]; pa.Whh1 = Whh_bf[1];
    pa.Wih2 = Wih_bf[2]; pa.Whh2 = Whh_bf[2];
    pa.inpP = inpP; pa.hPackB = hPackB;
    pa.ab1 = ab1; pa.aW2 = aW2; pa.ab2 = ab2; pa.fcb = fcb;
    pa.bih0 = bih[0]; pa.bhh0 = bhh[0];
    pa.bih1 = bih[1]; pa.bhh1 = bhh[1];
    pa.bih2 = bih[2]; pa.bhh2 = bhh[2];
    pa.aBuf = aBuf; pa.partM = partM; pa.partS = partS;
    pa.logits = logits; pa.cBuf = cBuf; pa.out = out;
    pa.bar = barBuf;
    persistent_all<<<NBLK, 512, 86016, stream>>>(pa);
    return;
  }

  // ---- legacy multi-kernel fallback (workspace too small for bf16 weights) ----
  #define HP(l, par)  (hPackB + ((l) * 2 + (par)) * 32768)
  #define CB(l, par)  (cBuf   + ((l) * 2 + (par)) * 32768)

  for (int t = 0; t < Tdim; t++){
    int pn = t & 1, po = 1 - pn;
    ushort* inpPt = inpP + (size_t)t * 49152;

    attn_a_gemm<<<64, 256, 0, stream>>>(W1h_bf, HP(2, po), ab1, aBuf);
    attn_score<<<128, 256, 0, stream>>>(aBuf, aW2, ab2, xW_bf, scBuf);
    attn_ctx2<<<96, 256, 0, stream>>>(scBuf, x_bf, inpPt);

    for (int l = 0; l < 3; l++){
      const ushort* bin = (l == 0) ? inpPt : HP(l - 1, pn);
      int kin = (l == 0) ? INPD : Hdim;
      lstm_layer<false><<<256, 256, 0, stream>>>(Wih[l], kin, Whh[l], bin, HP(l, po),
                                                 bih[l], bhh[l], CB(l, po), CB(l, pn), HP(l, pn));
    }

    fc_gemm<false><<<FCB, 512, 0, stream>>>(fcW, HP(2, pn), fcb, logits, partM, partS);
    lsm_write<<<dim3(Bdim, 32), 256, 0, stream>>>(logits, partM, partS, out, t);
  }
}